// Round 14
// baseline (277.368 us; speedup 1.0000x reference)
//
#include <hip/hip_runtime.h>

// SpeakerCrossAttention on MI355X (gfx950) — v14: fused one-pass, 32t tiles,
// 4 blocks/CU.
//   prep : per-batch chain -> attnn/biasb; W1f -> bf16 permuted (v11-13 verified)
//   main : v13's fused stage->GEMM->alpha->blend at 32t (v7 shape) with the
//          v12/v13 permuted-contiguous A loads that fix v7's request storm.
// Rationale: v13 (64t, 2 blocks/CU) = 240us total, phase-serial, HBM duty ~40%.
// 4 independent blocks/CU at uncorrelated phases -> near-continuous streaming.
// A L2 traffic doubles to 2GB (~60us aggregate) but stays under the 81us HBM
// floor and overlaps. LDS 40.1KB -> exactly 4 blocks/CU; VGPR ~110 uncapped.

typedef __attribute__((ext_vector_type(8))) short short8;     // 8 bf16 = 16B
typedef __attribute__((ext_vector_type(4))) unsigned short ushort4v;
typedef __attribute__((ext_vector_type(4))) float f32x4;

#define T_DIM 8192
#define D_DIM 512

__device__ __forceinline__ unsigned short f2bf(float x) {  // RTNE f32 -> bf16
  unsigned u = __builtin_bit_cast(unsigned, x);
  u = (u + 0x7fffu + ((u >> 16) & 1u)) >> 16;
  return (unsigned short)u;
}
__device__ __forceinline__ float bf2f(unsigned short h) {
  return __builtin_bit_cast(float, ((unsigned)h) << 16);
}

// ---------------- prep kernel (v12/v13-verified) ----------------
__global__ __launch_bounds__(512) void prep_kernel(
    const float* __restrict__ spk_in, const float* __restrict__ Wsp,
    const float* __restrict__ bsp,    const float* __restrict__ Wv,
    const float* __restrict__ bv,     const float* __restrict__ Wo,
    const float* __restrict__ bo,     const float* __restrict__ gma,
    const float* __restrict__ bta,    const float* __restrict__ Wg1,
    const float* __restrict__ bg1,
    float* __restrict__ attnn, float* __restrict__ biasb,
    unsigned short* __restrict__ w1fx)
{
  int tid = threadIdx.x;
  int blk = blockIdx.x;

  if (blk >= 16) {                    // W1f -> bf16 permuted:
    #pragma unroll                    // idx = ((w*16+kk)*4+ni)*512 + l*8 + e
    for (int i = 0; i < 4; ++i) {     // n = 64w+16ni+(l&15), d = 32kk+8(l>>4)+e
      int idx = (blk - 16) * 2048 + i * 512 + tid;
      int e  = idx & 7;
      int l  = (idx >> 3) & 63;
      int ni = (idx >> 9) & 3;
      int kk = (idx >> 11) & 15;
      int w  = (idx >> 15) & 7;
      int n = w * 64 + ni * 16 + (l & 15);
      int d = kk * 32 + (l >> 4) * 8 + e;
      w1fx[idx] = f2bf(Wg1[n * 1024 + d]);
    }
    return;
  }

  int b = blk;
  __shared__ __attribute__((aligned(16))) float s_spk[256];
  __shared__ __attribute__((aligned(16))) float s_x[512];
  __shared__ __attribute__((aligned(16))) float s_y[512];
  __shared__ float red[512];

  float se = (tid < 256) ? spk_in[b * 256 + tid] : 0.f;
  red[tid] = se * se;
  __syncthreads();
  for (int s = 256; s > 0; s >>= 1) {
    if (tid < s) red[tid] += red[tid + s];
    __syncthreads();
  }
  float scale = 1.f / fmaxf(sqrtf(red[0]), 1e-12f);
  if (tid < 256) s_spk[tid] = se * scale;
  __syncthreads();

  {
    const float* wr = Wsp + (size_t)tid * 256;
    f32x4 a4 = {0.f, 0.f, 0.f, 0.f};
    #pragma unroll 8
    for (int s2 = 0; s2 < 256; s2 += 4)
      a4 += (*(const f32x4*)(wr + s2)) * (*(const f32x4*)(s_spk + s2));
    s_x[tid] = a4[0] + a4[1] + a4[2] + a4[3] + bsp[tid];
  }
  __syncthreads();

  {
    const float* wr = Wv + (size_t)tid * 512;
    f32x4 a4 = {0.f, 0.f, 0.f, 0.f};
    #pragma unroll 8
    for (int s2 = 0; s2 < 512; s2 += 4)
      a4 += (*(const f32x4*)(wr + s2)) * (*(const f32x4*)(s_x + s2));
    s_y[tid] = a4[0] + a4[1] + a4[2] + a4[3] + bv[tid];
  }
  __syncthreads();

  float attnv;
  {
    const float* wr = Wo + (size_t)tid * 512;
    f32x4 a4 = {0.f, 0.f, 0.f, 0.f};
    #pragma unroll 8
    for (int s2 = 0; s2 < 512; s2 += 4)
      a4 += (*(const f32x4*)(wr + s2)) * (*(const f32x4*)(s_y + s2));
    attnv = a4[0] + a4[1] + a4[2] + a4[3] + bo[tid];
  }

  red[tid] = attnv;
  __syncthreads();
  for (int s = 256; s > 0; s >>= 1) {
    if (tid < s) red[tid] += red[tid + s];
    __syncthreads();
  }
  float mu = red[0] * (1.f / 512.f);
  __syncthreads();
  float dv = attnv - mu;
  red[tid] = dv * dv;
  __syncthreads();
  for (int s = 256; s > 0; s >>= 1) {
    if (tid < s) red[tid] += red[tid + s];
    __syncthreads();
  }
  float var = red[0] * (1.f / 512.f);
  float an = dv * rsqrtf(var + 1e-5f) * gma[tid] + bta[tid];
  s_x[tid] = an;
  attnn[b * 512 + tid] = an;
  __syncthreads();

  {
    const float* wr = Wg1 + (size_t)tid * 1024 + 512;
    f32x4 a4 = {0.f, 0.f, 0.f, 0.f};
    #pragma unroll 8
    for (int s2 = 0; s2 < 512; s2 += 4)
      a4 += (*(const f32x4*)(wr + s2)) * (*(const f32x4*)(s_x + s2));
    biasb[b * 512 + tid] = a4[0] + a4[1] + a4[2] + a4[3] + bg1[tid];
  }
}

// ---------------- fused main kernel: 32t tiles, 4 blocks/CU ----------------
// 4096 blocks (b = blk>>8, t0 = (blk&255)*32), 512 thr / 8 waves.
__global__ __launch_bounds__(512) void main_kernel(
    const float* __restrict__ feat, const unsigned short* __restrict__ w1fx,
    const float* __restrict__ attnn, const float* __restrict__ biasb,
    const float* __restrict__ wg2p,  const float* __restrict__ bg2p,
    float* __restrict__ out)
{
  __shared__ __attribute__((aligned(16))) unsigned short S[32 * 512]; // 32KB swz
  __shared__ __attribute__((aligned(16))) float s_bias[512];
  __shared__ __attribute__((aligned(16))) float s_wg2[512];
  __shared__ __attribute__((aligned(16))) float s_attn[512];
  __shared__ __attribute__((aligned(16))) float gpart[32 * 8];        // [t][w]
  __shared__ float als[32];

  int tid = threadIdx.x;
  int b  = blockIdx.x >> 8;
  int t0 = (blockIdx.x & 255) << 5;
  const float* fb = feat + (size_t)b * D_DIM * T_DIM + t0;
  char* Sb = (char*)S;

  // ---- stage (v7-verified mapping): thread (mt,mk) loads 4t x 8d ----
  int mt = tid & 7, mk = tid >> 3;       // mt: t-quad, mk: 0..63 d-quads
  int tt = mt * 4;

  f32x4 r[8];
  #pragma unroll
  for (int it = 0; it < 2; ++it) {
    int k0 = (mk + it * 64) * 4;
    #pragma unroll
    for (int q = 0; q < 4; ++q)
      r[it * 4 + q] = __builtin_nontemporal_load(
          (const f32x4*)(fb + (size_t)(k0 + q) * T_DIM + tt));
  }
  s_bias[tid] = biasb[b * 512 + tid];
  s_wg2[tid]  = wg2p[tid];
  s_attn[tid] = attnn[b * 512 + tid];
  __builtin_amdgcn_sched_barrier(0);     // all 8 loads issued before commits

  #pragma unroll
  for (int it = 0; it < 2; ++it) {
    int kbyte = (mk + it * 64) * 8;      // 4 d * 2B
    #pragma unroll
    for (int i = 0; i < 4; ++i) {
      ushort4v wv;
      #pragma unroll
      for (int q = 0; q < 4; ++q)
        wv[q] = f2bf(r[it * 4 + q][i]);
      int row = tt + i;
      int byte = (row << 10) + kbyte;
      byte ^= (row & 7) << 4;            // bank swizzle
      *(ushort4v*)(Sb + byte) = wv;      // ds_write_b64
    }
  }
  __syncthreads();

  // ---- GEMM (v12/v13-verified): permuted-contiguous af; t in [0,32) ----
  int l = tid & 63, w = tid >> 6;
  int g = l >> 4, cc = l & 15;
  int n0w = w * 64;
  const unsigned short* apw = w1fx + (size_t)w * 32768;  // wave's A slice
  int xsw = (cc & 7) << 4;
  int bb0 = (cc << 10) + g * 16;

  f32x4 acc[4][2];
  #pragma unroll
  for (int i = 0; i < 4; ++i) {
    acc[i][0] = (f32x4){0.f, 0.f, 0.f, 0.f};
    acc[i][1] = (f32x4){0.f, 0.f, 0.f, 0.f};
  }

  #pragma unroll 2
  for (int kk = 0; kk < 16; ++kk) {
    short8 af[4], bf[2];
    #pragma unroll
    for (int ni = 0; ni < 4; ++ni)
      af[ni] = *(const short8*)(apw + (kk * 4 + ni) * 512 + l * 8);  // 1KB contig
    #pragma unroll
    for (int tg = 0; tg < 2; ++tg)
      bf[tg] = *(const short8*)(Sb + ((bb0 + tg * 16384 + kk * 64) ^ xsw));
    #pragma unroll
    for (int ni = 0; ni < 4; ++ni) {
      acc[ni][0] = __builtin_amdgcn_mfma_f32_16x16x32_bf16(af[ni], bf[0], acc[ni][0], 0, 0, 0);
      acc[ni][1] = __builtin_amdgcn_mfma_f32_16x16x32_bf16(af[ni], bf[1], acc[ni][1], 0, 0, 0);
    }
  }
  // lane l, reg rr of acc[ni][tg]: h[n = n0w+16ni+4g+rr][t = 16tg+cc]

  // ---- alpha partials ----
  float p0 = 0.f, p1 = 0.f;
  #pragma unroll
  for (int ni = 0; ni < 4; ++ni) {
    #pragma unroll
    for (int rr = 0; rr < 4; ++rr) {
      int n = n0w + 16 * ni + 4 * g + rr;
      float bb = s_bias[n], ww = s_wg2[n];
      p0 += fmaxf(acc[ni][0][rr] + bb, 0.f) * ww;
      p1 += fmaxf(acc[ni][1][rr] + bb, 0.f) * ww;
    }
  }
  p0 += __shfl_xor(p0, 16); p0 += __shfl_xor(p0, 32);
  p1 += __shfl_xor(p1, 16); p1 += __shfl_xor(p1, 32);
  if (l < 16) {
    gpart[( 0 + l) * 8 + w] = p0;
    gpart[(16 + l) * 8 + w] = p1;
  }
  __syncthreads();
  if (tid < 32) {
    f32x4 a0 = *(const f32x4*)(&gpart[tid * 8]);
    f32x4 a1 = *(const f32x4*)(&gpart[tid * 8 + 4]);
    float gs = bg2p[0] + a0[0] + a0[1] + a0[2] + a0[3]
                       + a1[0] + a1[1] + a1[2] + a1[3];
    als[tid] = 1.f / (1.f + __expf(-gs));
  }
  __syncthreads();

  // ---- blend from LDS (swizzled reads, NT stores) ----
  {
    int tl = tid & 31, gg = tid >> 5;    // tl: t row, gg: 0..15
    float al = als[tl], om = 1.f - al;
    float* ob = out + (size_t)b * D_DIM * T_DIM + t0 + tl;
    int rbase = tl << 10, rsw = (tl & 7) << 4;
    #pragma unroll 4
    for (int it = 0; it < 8; ++it) {
      int d0 = it * 64 + gg * 4;
      ushort4v fv = *(const ushort4v*)(Sb + rbase + ((d0 * 2) ^ rsw));
      f32x4 an = *(const f32x4*)(&s_attn[d0]);
      #pragma unroll
      for (int i = 0; i < 4; ++i)
        __builtin_nontemporal_store(al * bf2f(fv[i]) + om * an[i],
                                    ob + (size_t)(d0 + i) * T_DIM);
    }
  }
}

extern "C" void kernel_launch(void* const* d_in, const int* in_sizes, int n_in,
                              void* d_out, int out_size, void* d_ws, size_t ws_size,
                              hipStream_t stream) {
  const float* features = (const float*)d_in[0];
  const float* spk      = (const float*)d_in[1];
  const float* Wsp      = (const float*)d_in[2];
  const float* bsp      = (const float*)d_in[3];
  const float* Wv       = (const float*)d_in[4];
  const float* bv       = (const float*)d_in[5];
  const float* Wo       = (const float*)d_in[6];
  const float* bo       = (const float*)d_in[7];
  const float* gma      = (const float*)d_in[8];
  const float* bta      = (const float*)d_in[9];
  const float* Wg1      = (const float*)d_in[10];
  const float* bg1      = (const float*)d_in[11];
  const float* Wg2      = (const float*)d_in[12];
  const float* bg2      = (const float*)d_in[13];
  float* out = (float*)d_out;

  // ws: attnn[8192] f32 | biasb[8192] f32 | w1fx[262144] bf16 (permuted)
  float* attnn = (float*)d_ws;
  float* biasb = attnn + 8192;
  unsigned short* w1fx = (unsigned short*)(biasb + 8192);

  prep_kernel<<<144, 512, 0, stream>>>(spk, Wsp, bsp, Wv, bv, Wo, bo, gma, bta,
                                       Wg1, bg1, attnn, biasb, w1fx);
  main_kernel<<<4096, 512, 0, stream>>>(features, w1fx, attnn, biasb, Wg2, bg2, out);
}

// Round 15
// 232.852 us; speedup vs baseline: 1.1912x; 1.1912x over previous
//
#include <hip/hip_runtime.h>

// SpeakerCrossAttention on MI355X (gfx950) — v15: v13 + asm-pinned stage loads.
//   prep : per-batch chain -> attnn/biasb; W1f -> bf16 permuted (verified)
//   main : v13's fused stage->GEMM->alpha->blend (64t, 2 blocks/CU), stage's
//          16 global loads forced into 16 live f32x4 regs via inline asm
//          (single HBM latency per block instead of compiler-batched ~6-8).
// v13=240us total. VGPR_Count evidence (32-56 across v5/v12/v14) shows the
// compiler was batching "parallel" stage loads through a few registers.

typedef __attribute__((ext_vector_type(8))) short short8;     // 8 bf16 = 16B
typedef __attribute__((ext_vector_type(4))) unsigned short ushort4v;
typedef __attribute__((ext_vector_type(4))) float f32x4;

#define T_DIM 8192
#define D_DIM 512

__device__ __forceinline__ unsigned short f2bf(float x) {  // RTNE f32 -> bf16
  unsigned u = __builtin_bit_cast(unsigned, x);
  u = (u + 0x7fffu + ((u >> 16) & 1u)) >> 16;
  return (unsigned short)u;
}
__device__ __forceinline__ float bf2f(unsigned short h) {
  return __builtin_bit_cast(float, ((unsigned)h) << 16);
}

// ---------------- prep kernel (v12/v13-verified) ----------------
__global__ __launch_bounds__(512) void prep_kernel(
    const float* __restrict__ spk_in, const float* __restrict__ Wsp,
    const float* __restrict__ bsp,    const float* __restrict__ Wv,
    const float* __restrict__ bv,     const float* __restrict__ Wo,
    const float* __restrict__ bo,     const float* __restrict__ gma,
    const float* __restrict__ bta,    const float* __restrict__ Wg1,
    const float* __restrict__ bg1,
    float* __restrict__ attnn, float* __restrict__ biasb,
    unsigned short* __restrict__ w1fx)
{
  int tid = threadIdx.x;
  int blk = blockIdx.x;

  if (blk >= 16) {                    // W1f -> bf16 permuted:
    #pragma unroll                    // idx = ((w*16+kk)*4+ni)*512 + l*8 + e
    for (int i = 0; i < 4; ++i) {     // n = 64w+16ni+(l&15), d = 32kk+8(l>>4)+e
      int idx = (blk - 16) * 2048 + i * 512 + tid;
      int e  = idx & 7;
      int l  = (idx >> 3) & 63;
      int ni = (idx >> 9) & 3;
      int kk = (idx >> 11) & 15;
      int w  = (idx >> 15) & 7;
      int n = w * 64 + ni * 16 + (l & 15);
      int d = kk * 32 + (l >> 4) * 8 + e;
      w1fx[idx] = f2bf(Wg1[n * 1024 + d]);
    }
    return;
  }

  int b = blk;
  __shared__ __attribute__((aligned(16))) float s_spk[256];
  __shared__ __attribute__((aligned(16))) float s_x[512];
  __shared__ __attribute__((aligned(16))) float s_y[512];
  __shared__ float red[512];

  float se = (tid < 256) ? spk_in[b * 256 + tid] : 0.f;
  red[tid] = se * se;
  __syncthreads();
  for (int s = 256; s > 0; s >>= 1) {
    if (tid < s) red[tid] += red[tid + s];
    __syncthreads();
  }
  float scale = 1.f / fmaxf(sqrtf(red[0]), 1e-12f);
  if (tid < 256) s_spk[tid] = se * scale;
  __syncthreads();

  {
    const float* wr = Wsp + (size_t)tid * 256;
    f32x4 a4 = {0.f, 0.f, 0.f, 0.f};
    #pragma unroll 8
    for (int s2 = 0; s2 < 256; s2 += 4)
      a4 += (*(const f32x4*)(wr + s2)) * (*(const f32x4*)(s_spk + s2));
    s_x[tid] = a4[0] + a4[1] + a4[2] + a4[3] + bsp[tid];
  }
  __syncthreads();

  {
    const float* wr = Wv + (size_t)tid * 512;
    f32x4 a4 = {0.f, 0.f, 0.f, 0.f};
    #pragma unroll 8
    for (int s2 = 0; s2 < 512; s2 += 4)
      a4 += (*(const f32x4*)(wr + s2)) * (*(const f32x4*)(s_x + s2));
    s_y[tid] = a4[0] + a4[1] + a4[2] + a4[3] + bv[tid];
  }
  __syncthreads();

  float attnv;
  {
    const float* wr = Wo + (size_t)tid * 512;
    f32x4 a4 = {0.f, 0.f, 0.f, 0.f};
    #pragma unroll 8
    for (int s2 = 0; s2 < 512; s2 += 4)
      a4 += (*(const f32x4*)(wr + s2)) * (*(const f32x4*)(s_y + s2));
    attnv = a4[0] + a4[1] + a4[2] + a4[3] + bo[tid];
  }

  red[tid] = attnv;
  __syncthreads();
  for (int s = 256; s > 0; s >>= 1) {
    if (tid < s) red[tid] += red[tid + s];
    __syncthreads();
  }
  float mu = red[0] * (1.f / 512.f);
  __syncthreads();
  float dv = attnv - mu;
  red[tid] = dv * dv;
  __syncthreads();
  for (int s = 256; s > 0; s >>= 1) {
    if (tid < s) red[tid] += red[tid + s];
    __syncthreads();
  }
  float var = red[0] * (1.f / 512.f);
  float an = dv * rsqrtf(var + 1e-5f) * gma[tid] + bta[tid];
  s_x[tid] = an;
  attnn[b * 512 + tid] = an;
  __syncthreads();

  {
    const float* wr = Wg1 + (size_t)tid * 1024 + 512;
    f32x4 a4 = {0.f, 0.f, 0.f, 0.f};
    #pragma unroll 8
    for (int s2 = 0; s2 < 512; s2 += 4)
      a4 += (*(const f32x4*)(wr + s2)) * (*(const f32x4*)(s_x + s2));
    biasb[b * 512 + tid] = a4[0] + a4[1] + a4[2] + a4[3] + bg1[tid];
  }
}

// ---------------- fused main kernel (v13 shape, pinned stage) ----------------
// 2048 blocks (b = blk>>7, t0 = (blk&127)*64), 512 thr / 8 waves, 2 blocks/CU.
__global__ __launch_bounds__(512) void main_kernel(
    const float* __restrict__ feat, const unsigned short* __restrict__ w1fx,
    const float* __restrict__ attnn, const float* __restrict__ biasb,
    const float* __restrict__ wg2p,  const float* __restrict__ bg2p,
    float* __restrict__ out)
{
  __shared__ __attribute__((aligned(16))) unsigned short S[64 * 512]; // 64KB swz
  __shared__ __attribute__((aligned(16))) float s_bias[512];
  __shared__ __attribute__((aligned(16))) float s_wg2[512];
  __shared__ __attribute__((aligned(16))) float s_attn[512];
  __shared__ __attribute__((aligned(16))) float gpart[64 * 8];        // [t][w]
  __shared__ float als[64];

  int tid = threadIdx.x;
  int b  = blockIdx.x >> 7;
  int t0 = (blockIdx.x & 127) << 6;
  const float* fb = feat + (size_t)b * D_DIM * T_DIM + t0;
  char* Sb = (char*)S;

  // ---- stage: 16 asm-pinned loads (ALL in flight), one vmcnt, commit ----
  int mt = tid & 15, mk = tid >> 4;      // mk 0..31
  int tt = mt * 4;

  f32x4 r[16];
  {
    const float* ap[16];
    #pragma unroll
    for (int it = 0; it < 2; ++it) {
      int k0 = mk * 8 + it * 256;
      #pragma unroll
      for (int q = 0; q < 8; ++q)
        ap[it * 8 + q] = fb + (size_t)(k0 + q) * T_DIM + tt;
    }
    #pragma unroll
    for (int i = 0; i < 16; ++i)
      asm volatile("global_load_dwordx4 %0, %1, off"
                   : "=v"(r[i]) : "v"(ap[i]) : "memory");
  }
  s_bias[tid] = biasb[b * 512 + tid];
  s_wg2[tid]  = wg2p[tid];
  s_attn[tid] = attnn[b * 512 + tid];
  asm volatile("s_waitcnt vmcnt(0)" ::: "memory");
  __builtin_amdgcn_sched_barrier(0);

  #pragma unroll
  for (int it = 0; it < 2; ++it) {
    int kbyte = (mk * 8 + it * 256) * 2;
    #pragma unroll
    for (int i = 0; i < 4; ++i) {
      short8 wv;
      #pragma unroll
      for (int q = 0; q < 8; ++q)
        wv[q] = (short)f2bf(r[it * 8 + q][i]);
      int row = tt + i;
      int byte = (row << 10) + kbyte;
      byte ^= (row & 7) << 4;            // bank swizzle
      *(short8*)(Sb + byte) = wv;        // ds_write_b128
    }
  }
  __syncthreads();

  // ---- GEMM (v12/v13-verified): permuted-contiguous af ----
  int l = tid & 63, w = tid >> 6;
  int g = l >> 4, cc = l & 15;
  int n0w = w * 64;
  const unsigned short* apw = w1fx + (size_t)w * 32768;  // wave's A slice
  int xsw = (cc & 7) << 4;
  int bb0 = (cc << 10) + g * 16;

  f32x4 acc[4][4];
  #pragma unroll
  for (int i = 0; i < 4; ++i)
    #pragma unroll
    for (int j = 0; j < 4; ++j)
      acc[i][j] = (f32x4){0.f, 0.f, 0.f, 0.f};

  #pragma unroll 2
  for (int kk = 0; kk < 16; ++kk) {
    short8 af[4], bf[4];
    #pragma unroll
    for (int ni = 0; ni < 4; ++ni)
      af[ni] = *(const short8*)(apw + (kk * 4 + ni) * 512 + l * 8);  // 1KB contig
    #pragma unroll
    for (int tg = 0; tg < 4; ++tg)
      bf[tg] = *(const short8*)(Sb + ((bb0 + tg * 16384 + kk * 64) ^ xsw));
    #pragma unroll
    for (int ni = 0; ni < 4; ++ni)
      #pragma unroll
      for (int tg = 0; tg < 4; ++tg)
        acc[ni][tg] = __builtin_amdgcn_mfma_f32_16x16x32_bf16(
            af[ni], bf[tg], acc[ni][tg], 0, 0, 0);
  }
  // lane l, reg rr of acc[ni][tg]: h[n = n0w+16ni+4g+rr][t = 16tg+cc]

  // ---- alpha partials ----
  float p0 = 0.f, p1 = 0.f, p2 = 0.f, p3 = 0.f;
  #pragma unroll
  for (int ni = 0; ni < 4; ++ni) {
    #pragma unroll
    for (int rr = 0; rr < 4; ++rr) {
      int n = n0w + 16 * ni + 4 * g + rr;
      float bb = s_bias[n], ww = s_wg2[n];
      p0 += fmaxf(acc[ni][0][rr] + bb, 0.f) * ww;
      p1 += fmaxf(acc[ni][1][rr] + bb, 0.f) * ww;
      p2 += fmaxf(acc[ni][2][rr] + bb, 0.f) * ww;
      p3 += fmaxf(acc[ni][3][rr] + bb, 0.f) * ww;
    }
  }
  p0 += __shfl_xor(p0, 16); p0 += __shfl_xor(p0, 32);
  p1 += __shfl_xor(p1, 16); p1 += __shfl_xor(p1, 32);
  p2 += __shfl_xor(p2, 16); p2 += __shfl_xor(p2, 32);
  p3 += __shfl_xor(p3, 16); p3 += __shfl_xor(p3, 32);
  if (l < 16) {
    gpart[( 0 + l) * 8 + w] = p0;
    gpart[(16 + l) * 8 + w] = p1;
    gpart[(32 + l) * 8 + w] = p2;
    gpart[(48 + l) * 8 + w] = p3;
  }
  __syncthreads();
  if (tid < 64) {
    f32x4 a0 = *(const f32x4*)(&gpart[tid * 8]);
    f32x4 a1 = *(const f32x4*)(&gpart[tid * 8 + 4]);
    float gs = bg2p[0] + a0[0] + a0[1] + a0[2] + a0[3]
                       + a1[0] + a1[1] + a1[2] + a1[3];
    als[tid] = 1.f / (1.f + __expf(-gs));
  }
  __syncthreads();

  // ---- blend from LDS (swizzled reads, NT stores) ----
  {
    int tl = tid & 63, gg = tid >> 6;    // tl: t row, gg: 0..7
    float al = als[tl], om = 1.f - al;
    float* ob = out + (size_t)b * D_DIM * T_DIM + t0 + tl;
    int rbase = tl << 10, rsw = (tl & 7) << 4;
    #pragma unroll 4
    for (int it = 0; it < 16; ++it) {
      int d0 = it * 32 + gg * 4;
      ushort4v fv = *(const ushort4v*)(Sb + rbase + ((d0 * 2) ^ rsw));
      f32x4 an = *(const f32x4*)(&s_attn[d0]);
      #pragma unroll
      for (int i = 0; i < 4; ++i)
        __builtin_nontemporal_store(al * bf2f(fv[i]) + om * an[i],
                                    ob + (size_t)(d0 + i) * T_DIM);
    }
  }
}

extern "C" void kernel_launch(void* const* d_in, const int* in_sizes, int n_in,
                              void* d_out, int out_size, void* d_ws, size_t ws_size,
                              hipStream_t stream) {
  const float* features = (const float*)d_in[0];
  const float* spk      = (const float*)d_in[1];
  const float* Wsp      = (const float*)d_in[2];
  const float* bsp      = (const float*)d_in[3];
  const float* Wv       = (const float*)d_in[4];
  const float* bv       = (const float*)d_in[5];
  const float* Wo       = (const float*)d_in[6];
  const float* bo       = (const float*)d_in[7];
  const float* gma      = (const float*)d_in[8];
  const float* bta      = (const float*)d_in[9];
  const float* Wg1      = (const float*)d_in[10];
  const float* bg1      = (const float*)d_in[11];
  const float* Wg2      = (const float*)d_in[12];
  const float* bg2      = (const float*)d_in[13];
  float* out = (float*)d_out;

  // ws: attnn[8192] f32 | biasb[8192] f32 | w1fx[262144] bf16 (permuted)
  float* attnn = (float*)d_ws;
  float* biasb = attnn + 8192;
  unsigned short* w1fx = (unsigned short*)(biasb + 8192);

  prep_kernel<<<144, 512, 0, stream>>>(spk, Wsp, bsp, Wv, bv, Wo, bo, gma, bta,
                                       Wg1, bg1, attnn, biasb, w1fx);
  main_kernel<<<2048, 512, 0, stream>>>(features, w1fx, attnn, biasb, Wg2, bg2, out);
}